// Round 2
// baseline (473.517 us; speedup 1.0000x reference)
//
#include <hip/hip_runtime.h>
#include <hip/hip_bf16.h>

static constexpr int T = 512;
static constexpr int B = 4096;

__device__ __forceinline__ float frcp_(float x) { return __builtin_amdgcn_rcpf(x); }
__device__ __forceinline__ float sig_(float x) { return frcp_(1.0f + __expf(-x)); }
__device__ __forceinline__ float tanhf_(float x) { return 1.0f - 2.0f * frcp_(1.0f + __expf(2.0f * x)); }

// Compiler memory fence + scheduling barrier. Each 16-lane group lies within
// one wave; same-wave LDS ops complete in order, so no s_waitcnt/s_barrier
// is needed — only compiler reordering must be prevented.
#define WAVE_SYNC() do { asm volatile("" ::: "memory"); \
                         __builtin_amdgcn_wave_barrier(); \
                         asm volatile("" ::: "memory"); } while (0)

// ---------------- Kernel 1: layer-0 backward scan ----------------
// 16 lanes per sequence; lane j owns gate rows j, 16+j, 32+j.
__global__ void __launch_bounds__(256) k_l0_bwd(
    const float* __restrict__ x,     // [B,T]
    const float* __restrict__ Wih,   // [48,1]
    const float* __restrict__ Whh,   // [48,16]
    const float* __restrict__ bih,   // [48]
    const float* __restrict__ bhh,   // [48]
    __hip_bfloat16* __restrict__ y0b) // [T,B,16] bf16
{
    __shared__ float hbuf[256];
    const int tid = threadIdx.x;
    const int g = tid >> 4, j = tid & 15;
    const int b = blockIdx.x * 16 + g;

    float wr[16], wz[16], wn[16];
#pragma unroll
    for (int k = 0; k < 16; ++k) {
        wr[k] = Whh[j * 16 + k];
        wz[k] = Whh[(16 + j) * 16 + k];
        wn[k] = Whh[(32 + j) * 16 + k];
    }
    const float wxr = Wih[j], wxz = Wih[16 + j], wxn = Wih[32 + j];
    const float br  = bih[j] + bhh[j];
    const float bz  = bih[16 + j] + bhh[16 + j];
    const float bin_ = bih[32 + j];
    const float bhn  = bhh[32 + j];

    float hj = 0.0f;
    float hv[16];
#pragma unroll
    for (int k = 0; k < 16; ++k) hv[k] = 0.0f;

    const float* xrow = x + (size_t)b * T;
    __hip_bfloat16* yp = y0b + ((size_t)(T - 1) * B + b) * 16 + j;
    float xv = xrow[T - 1];
    for (int t = T - 1; t >= 0; --t) {
        float xn = (t > 0) ? xrow[t - 1] : 0.0f;   // 1-step prefetch
        float ar = fmaf(xv, wxr, br);
        float az = fmaf(xv, wxz, bz);
        float ai = fmaf(xv, wxn, bin_);
        float hn = bhn;
#pragma unroll
        for (int k = 0; k < 16; ++k) {
            ar = fmaf(wr[k], hv[k], ar);
            az = fmaf(wz[k], hv[k], az);
            hn = fmaf(wn[k], hv[k], hn);
        }
        float r = sig_(ar), z = sig_(az);
        float n = tanhf_(fmaf(r, hn, ai));
        hj = fmaf(z, hj - n, n);           // (1-z)*n + z*h
        *yp = __hip_bfloat16(hj);
        yp -= (size_t)B * 16;
        // wave-synchronous h exchange
        hbuf[tid] = hj;
        WAVE_SYNC();
#pragma unroll
        for (int q = 0; q < 4; ++q) {
            float4 v = *reinterpret_cast<const float4*>(&hbuf[g * 16 + 4 * q]);
            hv[4 * q + 0] = v.x; hv[4 * q + 1] = v.y;
            hv[4 * q + 2] = v.z; hv[4 * q + 3] = v.w;
        }
        WAVE_SYNC();
        xv = xn;
    }
}

// -------- Kernel 2: fused L0-fwd + L1-fwd scan, L1-bwd single step --------
__global__ void __launch_bounds__(256) k_fused(
    const float* __restrict__ x,
    const float* __restrict__ Wih0, const float* __restrict__ Whh0,
    const float* __restrict__ bih0, const float* __restrict__ bhh0,
    const float* __restrict__ Wih1, const float* __restrict__ Whh1,   // l1 fwd: [48,32],[48,16]
    const float* __restrict__ bih1, const float* __restrict__ bhh1,
    const float* __restrict__ Wih1b, const float* __restrict__ Whh1b, // l1 bwd
    const float* __restrict__ bih1b, const float* __restrict__ bhh1b,
    const __hip_bfloat16* __restrict__ y0b, // [T,B,16]
    float* __restrict__ out)                 // [B,32]
{
    __shared__ float h0buf[256], h1buf[256];
    const int tid = threadIdx.x;
    const int g = tid >> 4, j = tid & 15;
    const int b = blockIdx.x * 16 + g;

    float w0r[16], w0z[16], w0n[16];
#pragma unroll
    for (int k = 0; k < 16; ++k) {
        w0r[k] = Whh0[j * 16 + k];
        w0z[k] = Whh0[(16 + j) * 16 + k];
        w0n[k] = Whh0[(32 + j) * 16 + k];
    }
    const float wx0r = Wih0[j], wx0z = Wih0[16 + j], wx0n = Wih0[32 + j];
    const float b0r = bih0[j] + bhh0[j];
    const float b0z = bih0[16 + j] + bhh0[16 + j];
    const float b0in = bih0[32 + j];
    const float b0hn = bhh0[32 + j];

    float w1r[32], w1z[32], w1n[32];
#pragma unroll
    for (int k = 0; k < 32; ++k) {
        w1r[k] = Wih1[j * 32 + k];
        w1z[k] = Wih1[(16 + j) * 32 + k];
        w1n[k] = Wih1[(32 + j) * 32 + k];
    }
    float u1r[16], u1z[16], u1n[16];
#pragma unroll
    for (int k = 0; k < 16; ++k) {
        u1r[k] = Whh1[j * 16 + k];
        u1z[k] = Whh1[(16 + j) * 16 + k];
        u1n[k] = Whh1[(32 + j) * 16 + k];
    }
    const float b1r = bih1[j] + bhh1[j];
    const float b1z = bih1[16 + j] + bhh1[16 + j];
    const float b1in = bih1[32 + j];
    const float b1hn = bhh1[32 + j];

    float h0j = 0.0f, h1j = 0.0f;
    float h0v[16], h1v[16];
#pragma unroll
    for (int k = 0; k < 16; ++k) { h0v[k] = 0.0f; h1v[k] = 0.0f; }

    const float* xrow = x + (size_t)b * T;
    const unsigned* ybase = reinterpret_cast<const unsigned*>(y0b) + (size_t)b * 8; // 8 dwords = 16 bf16
    uint4 ya  = *reinterpret_cast<const uint4*>(ybase);
    uint4 yb4 = *reinterpret_cast<const uint4*>(ybase + 4);
    float xv = xrow[0];

    for (int t = 0; t < T; ++t) {
        uint4 na = ya, nb4 = yb4;
        float xn = xv;
        if (t < T - 1) {  // uniform branch; 1-step prefetch
            const unsigned* np = ybase + (size_t)(t + 1) * B * 8;
            na  = *reinterpret_cast<const uint4*>(np);
            nb4 = *reinterpret_cast<const uint4*>(np + 4);
            xn  = xrow[t + 1];
        }

        // ---- L0 forward step
        float ar = fmaf(xv, wx0r, b0r);
        float az = fmaf(xv, wx0z, b0z);
        float ai = fmaf(xv, wx0n, b0in);
        float hn = b0hn;
#pragma unroll
        for (int k = 0; k < 16; ++k) {
            ar = fmaf(w0r[k], h0v[k], ar);
            az = fmaf(w0z[k], h0v[k], az);
            hn = fmaf(w0n[k], h0v[k], hn);
        }
        {
            float r = sig_(ar), z = sig_(az);
            float n = tanhf_(fmaf(r, hn, ai));
            h0j = fmaf(z, h0j - n, n);
        }
        h0buf[tid] = h0j;
        WAVE_SYNC();
#pragma unroll
        for (int q = 0; q < 4; ++q) {
            float4 v = *reinterpret_cast<const float4*>(&h0buf[g * 16 + 4 * q]);
            h0v[4 * q + 0] = v.x; h0v[4 * q + 1] = v.y;
            h0v[4 * q + 2] = v.z; h0v[4 * q + 3] = v.w;
        }
        WAVE_SYNC();

        // ---- unpack y0b(t) (bf16 -> f32)
        float yv[16];
        {
            const unsigned uu[8] = { ya.x, ya.y, ya.z, ya.w, yb4.x, yb4.y, yb4.z, yb4.w };
#pragma unroll
            for (int q = 0; q < 8; ++q) {
                union { unsigned a; float f; } lo, hi;
                lo.a = uu[q] << 16;
                hi.a = uu[q] & 0xFFFF0000u;
                yv[2 * q]     = lo.f;
                yv[2 * q + 1] = hi.f;
            }
        }

        // ---- L1 forward step (input = [h0f(16), y0b(16)])
        float cr = b1r, cz = b1z, ci = b1in, chn = b1hn;
#pragma unroll
        for (int k = 0; k < 16; ++k) {
            cr = fmaf(w1r[k], h0v[k], cr);
            cz = fmaf(w1z[k], h0v[k], cz);
            ci = fmaf(w1n[k], h0v[k], ci);
        }
#pragma unroll
        for (int k = 0; k < 16; ++k) {
            cr = fmaf(w1r[16 + k], yv[k], cr);
            cz = fmaf(w1z[16 + k], yv[k], cz);
            ci = fmaf(w1n[16 + k], yv[k], ci);
        }
#pragma unroll
        for (int k = 0; k < 16; ++k) {
            cr  = fmaf(u1r[k], h1v[k], cr);
            cz  = fmaf(u1z[k], h1v[k], cz);
            chn = fmaf(u1n[k], h1v[k], chn);
        }
        {
            float r = sig_(cr), z = sig_(cz);
            float n = tanhf_(fmaf(r, chn, ci));
            h1j = fmaf(z, h1j - n, n);
        }
        h1buf[tid] = h1j;
        WAVE_SYNC();
#pragma unroll
        for (int q = 0; q < 4; ++q) {
            float4 v = *reinterpret_cast<const float4*>(&h1buf[g * 16 + 4 * q]);
            h1v[4 * q + 0] = v.x; h1v[4 * q + 1] = v.y;
            h1v[4 * q + 2] = v.z; h1v[4 * q + 3] = v.w;
        }
        WAVE_SYNC();

        ya = na; yb4 = nb4; xv = xn;
    }

    // forward half of the output
    out[(size_t)b * 32 + j] = h1j;

    // ---- L1 backward, single step at t=T-1 from h=0.
    // ya/yb4 still hold y0b[T-1]; h0v holds h0f(T-1).
    float gr = bih1b[j] + bhh1b[j];
    float gz = bih1b[16 + j] + bhh1b[16 + j];
    float gi = bih1b[32 + j];
    const float ghn = bhh1b[32 + j];
    float yv[16];
    {
        const unsigned uu[8] = { ya.x, ya.y, ya.z, ya.w, yb4.x, yb4.y, yb4.z, yb4.w };
#pragma unroll
        for (int q = 0; q < 8; ++q) {
            union { unsigned a; float f; } lo, hi;
            lo.a = uu[q] << 16;
            hi.a = uu[q] & 0xFFFF0000u;
            yv[2 * q]     = lo.f;
            yv[2 * q + 1] = hi.f;
        }
    }
#pragma unroll
    for (int k = 0; k < 16; ++k) {
        gr = fmaf(Wih1b[j * 32 + k],        h0v[k], gr);
        gz = fmaf(Wih1b[(16 + j) * 32 + k], h0v[k], gz);
        gi = fmaf(Wih1b[(32 + j) * 32 + k], h0v[k], gi);
    }
#pragma unroll
    for (int k = 0; k < 16; ++k) {
        gr = fmaf(Wih1b[j * 32 + 16 + k],        yv[k], gr);
        gz = fmaf(Wih1b[(16 + j) * 32 + 16 + k], yv[k], gz);
        gi = fmaf(Wih1b[(32 + j) * 32 + 16 + k], yv[k], gi);
    }
    float rb = sig_(gr), zb = sig_(gz);
    float nb2 = tanhf_(fmaf(rb, ghn, gi));
    out[(size_t)b * 32 + 16 + j] = (1.0f - zb) * nb2;
}

extern "C" void kernel_launch(void* const* d_in, const int* in_sizes, int n_in,
                              void* d_out, int out_size, void* d_ws, size_t ws_size,
                              hipStream_t stream) {
    const float* x     = (const float*)d_in[0];
    const float* Wih0f = (const float*)d_in[1];
    const float* Whh0f = (const float*)d_in[2];
    const float* bih0f = (const float*)d_in[3];
    const float* bhh0f = (const float*)d_in[4];
    const float* Wih0b = (const float*)d_in[5];
    const float* Whh0b = (const float*)d_in[6];
    const float* bih0b = (const float*)d_in[7];
    const float* bhh0b = (const float*)d_in[8];
    const float* Wih1f = (const float*)d_in[9];
    const float* Whh1f = (const float*)d_in[10];
    const float* bih1f = (const float*)d_in[11];
    const float* bhh1f = (const float*)d_in[12];
    const float* Wih1b = (const float*)d_in[13];
    const float* Whh1b = (const float*)d_in[14];
    const float* bih1b = (const float*)d_in[15];
    const float* bhh1b = (const float*)d_in[16];
    __hip_bfloat16* y0b = (__hip_bfloat16*)d_ws;   // [T,B,16] bf16 = 64 MiB
    float* out = (float*)d_out;

    // 16 sequences per block (16 groups x 16 lanes) -> B/16 = 256 blocks.
    dim3 grid(B / 16);
    dim3 block(256);
    hipLaunchKernelGGL(k_l0_bwd, grid, block, 0, stream,
                       x, Wih0b, Whh0b, bih0b, bhh0b, y0b);
    hipLaunchKernelGGL(k_fused, grid, block, 0, stream,
                       x, Wih0f, Whh0f, bih0f, bhh0f,
                       Wih1f, Whh1f, bih1f, bhh1f,
                       Wih1b, Whh1b, bih1b, bhh1b,
                       y0b, out);
}

// Round 3
// 385.804 us; speedup vs baseline: 1.2274x; 1.2274x over previous
//
#include <hip/hip_runtime.h>
#include <hip/hip_bf16.h>

typedef float v2f __attribute__((ext_vector_type(2)));

static constexpr int T = 512;
static constexpr int B = 4096;

__device__ __forceinline__ float frcp_(float x) { return __builtin_amdgcn_rcpf(x); }
__device__ __forceinline__ float sig_(float x) { return frcp_(1.0f + __expf(-x)); }
__device__ __forceinline__ float tanh_(float x) { return 1.0f - 2.0f * frcp_(1.0f + __expf(2.0f * x)); }

// Compiler fence + scheduling barrier. Each 16-lane group lies inside one
// wave; same-wave LDS ops complete in order, so no s_waitcnt/s_barrier is
// needed — only compiler reordering must be prevented.
#define WAVE_SYNC() do { asm volatile("" ::: "memory"); \
                         __builtin_amdgcn_wave_barrier(); \
                         asm volatile("" ::: "memory"); } while (0)

__device__ __forceinline__ v2f bf2_unpack(unsigned u) {
    union { unsigned a; float f; } lo, hi;
    lo.a = u << 16;
    hi.a = u & 0xFFFF0000u;
    v2f r; r[0] = lo.f; r[1] = hi.f;
    return r;
}

// ---------------- Kernel 1: layer-0 backward scan ----------------
// 16 lanes per sequence; lane j owns gate rows j, 16+j, 32+j.
__global__ void __launch_bounds__(256, 1) k_l0_bwd(
    const float* __restrict__ x,      // [B,T]
    const float* __restrict__ Wih,    // [48,1]
    const float* __restrict__ Whh,    // [48,16]
    const float* __restrict__ bih,    // [48]
    const float* __restrict__ bhh,    // [48]
    __hip_bfloat16* __restrict__ y0b) // [T,B,16] bf16
{
    __shared__ float hbuf[256];
    const int tid = threadIdx.x;
    const int g = tid >> 4, j = tid & 15;
    const int b = blockIdx.x * 16 + g;

    v2f wr[8], wz[8], wn[8];
    {
        const v2f* pr = reinterpret_cast<const v2f*>(Whh + j * 16);
        const v2f* pz = reinterpret_cast<const v2f*>(Whh + (16 + j) * 16);
        const v2f* pn = reinterpret_cast<const v2f*>(Whh + (32 + j) * 16);
#pragma unroll
        for (int q = 0; q < 8; ++q) { wr[q] = pr[q]; wz[q] = pz[q]; wn[q] = pn[q]; }
    }
    const float wxr = Wih[j], wxz = Wih[16 + j], wxn = Wih[32 + j];
    const float br   = bih[j] + bhh[j];
    const float bz   = bih[16 + j] + bhh[16 + j];
    const float bin_ = bih[32 + j];
    const float bhn  = bhh[32 + j];

    float hj = 0.0f;
    v2f hv[8];
#pragma unroll
    for (int q = 0; q < 8; ++q) { hv[q][0] = 0.0f; hv[q][1] = 0.0f; }

    const float* xrow = x + (size_t)b * T;
    __hip_bfloat16* yp = y0b + ((size_t)(T - 1) * B + b) * 16 + j;
    float xv = xrow[T - 1];
    for (int t = T - 1; t >= 0; --t) {
        float xn = xrow[(t > 0) ? t - 1 : 0];   // 1-step prefetch (clamped)
        v2f ar0{}, ar1{}, az0{}, az1{}, an0{}, an1{};
#pragma unroll
        for (int q = 0; q < 4; ++q) {
            ar0 += wr[q] * hv[q];
            az0 += wz[q] * hv[q];
            an0 += wn[q] * hv[q];
        }
#pragma unroll
        for (int q = 4; q < 8; ++q) {
            ar1 += wr[q] * hv[q];
            az1 += wz[q] * hv[q];
            an1 += wn[q] * hv[q];
        }
        float ar = (ar0[0] + ar0[1]) + (ar1[0] + ar1[1]) + fmaf(xv, wxr, br);
        float az = (az0[0] + az0[1]) + (az1[0] + az1[1]) + fmaf(xv, wxz, bz);
        float hn = (an0[0] + an0[1]) + (an1[0] + an1[1]) + bhn;
        float ai = fmaf(xv, wxn, bin_);
        float r = sig_(ar), z = sig_(az);
        float n = tanh_(fmaf(r, hn, ai));
        hj = fmaf(z, hj - n, n);           // (1-z)*n + z*h
        *yp = __hip_bfloat16(hj);
        yp -= (size_t)B * 16;
        // wave-synchronous h exchange
        hbuf[tid] = hj;
        WAVE_SYNC();
#pragma unroll
        for (int q = 0; q < 4; ++q) {
            float4 v = *reinterpret_cast<const float4*>(&hbuf[g * 16 + 4 * q]);
            hv[2 * q + 0][0] = v.x; hv[2 * q + 0][1] = v.y;
            hv[2 * q + 1][0] = v.z; hv[2 * q + 1][1] = v.w;
        }
        WAVE_SYNC();
        xv = xn;
    }
}

// -------- Kernel 2: fused L0-fwd + L1-fwd scan, L1-bwd single step --------
__global__ void __launch_bounds__(256, 1) k_fused(
    const float* __restrict__ x,
    const float* __restrict__ Wih0, const float* __restrict__ Whh0,
    const float* __restrict__ bih0, const float* __restrict__ bhh0,
    const float* __restrict__ Wih1, const float* __restrict__ Whh1,   // l1 fwd: [48,32],[48,16]
    const float* __restrict__ bih1, const float* __restrict__ bhh1,
    const float* __restrict__ Wih1b, const float* __restrict__ Whh1b, // l1 bwd
    const float* __restrict__ bih1b, const float* __restrict__ bhh1b,
    const __hip_bfloat16* __restrict__ y0b, // [T,B,16]
    float* __restrict__ out)                 // [B,32]
{
    __shared__ float h0buf[256], h1buf[256];
    const int tid = threadIdx.x;
    const int g = tid >> 4, j = tid & 15;
    const int b = blockIdx.x * 16 + g;

    // L0 forward weights
    v2f w0r[8], w0z[8], w0n[8];
    {
        const v2f* pr = reinterpret_cast<const v2f*>(Whh0 + j * 16);
        const v2f* pz = reinterpret_cast<const v2f*>(Whh0 + (16 + j) * 16);
        const v2f* pn = reinterpret_cast<const v2f*>(Whh0 + (32 + j) * 16);
#pragma unroll
        for (int q = 0; q < 8; ++q) { w0r[q] = pr[q]; w0z[q] = pz[q]; w0n[q] = pn[q]; }
    }
    const float wx0r = Wih0[j], wx0z = Wih0[16 + j], wx0n = Wih0[32 + j];
    const float b0r = bih0[j] + bhh0[j];
    const float b0z = bih0[16 + j] + bhh0[16 + j];
    const float b0in = bih0[32 + j];
    const float b0hn = bhh0[32 + j];

    // L1 forward weights: Wih1 rows are 32 wide (cols 0..15 = h0f, 16..31 = y0b)
    v2f w1r[16], w1z[16], w1n[16];
    {
        const v2f* pr = reinterpret_cast<const v2f*>(Wih1 + j * 32);
        const v2f* pz = reinterpret_cast<const v2f*>(Wih1 + (16 + j) * 32);
        const v2f* pn = reinterpret_cast<const v2f*>(Wih1 + (32 + j) * 32);
#pragma unroll
        for (int q = 0; q < 16; ++q) { w1r[q] = pr[q]; w1z[q] = pz[q]; w1n[q] = pn[q]; }
    }
    v2f u1r[8], u1z[8], u1n[8];
    {
        const v2f* pr = reinterpret_cast<const v2f*>(Whh1 + j * 16);
        const v2f* pz = reinterpret_cast<const v2f*>(Whh1 + (16 + j) * 16);
        const v2f* pn = reinterpret_cast<const v2f*>(Whh1 + (32 + j) * 16);
#pragma unroll
        for (int q = 0; q < 8; ++q) { u1r[q] = pr[q]; u1z[q] = pz[q]; u1n[q] = pn[q]; }
    }
    const float b1r = bih1[j] + bhh1[j];
    const float b1z = bih1[16 + j] + bhh1[16 + j];
    const float b1in = bih1[32 + j];
    const float b1hn = bhh1[32 + j];

    float h0j = 0.0f, h1j = 0.0f;
    v2f h0v[8], h1v[8];
#pragma unroll
    for (int q = 0; q < 8; ++q) {
        h0v[q][0] = 0.0f; h0v[q][1] = 0.0f;
        h1v[q][0] = 0.0f; h1v[q][1] = 0.0f;
    }

    const float* xrow = x + (size_t)b * T;
    const unsigned* ybase = reinterpret_cast<const unsigned*>(y0b) + (size_t)b * 8; // 8 dwords = 16 bf16
    uint4 ya  = *reinterpret_cast<const uint4*>(ybase);
    uint4 yb4 = *reinterpret_cast<const uint4*>(ybase + 4);
    float xv = xrow[0];

    for (int t = 0; t < T; ++t) {
        const int tc = (t < T - 1) ? t + 1 : t;   // clamped 1-step prefetch
        const unsigned* np = ybase + (size_t)tc * B * 8;
        uint4 na  = *reinterpret_cast<const uint4*>(np);
        uint4 nb4 = *reinterpret_cast<const uint4*>(np + 4);
        float xn  = xrow[tc];

        // ---- L0 forward step
        {
            v2f ar0{}, ar1{}, az0{}, az1{}, an0{}, an1{};
#pragma unroll
            for (int q = 0; q < 4; ++q) {
                ar0 += w0r[q] * h0v[q];
                az0 += w0z[q] * h0v[q];
                an0 += w0n[q] * h0v[q];
            }
#pragma unroll
            for (int q = 4; q < 8; ++q) {
                ar1 += w0r[q] * h0v[q];
                az1 += w0z[q] * h0v[q];
                an1 += w0n[q] * h0v[q];
            }
            float ar = (ar0[0] + ar0[1]) + (ar1[0] + ar1[1]) + fmaf(xv, wx0r, b0r);
            float az = (az0[0] + az0[1]) + (az1[0] + az1[1]) + fmaf(xv, wx0z, b0z);
            float hn = (an0[0] + an0[1]) + (an1[0] + an1[1]) + b0hn;
            float ai = fmaf(xv, wx0n, b0in);
            float r = sig_(ar), z = sig_(az);
            float n = tanh_(fmaf(r, hn, ai));
            h0j = fmaf(z, h0j - n, n);
        }
        h0buf[tid] = h0j;
        WAVE_SYNC();
#pragma unroll
        for (int q = 0; q < 4; ++q) {
            float4 v = *reinterpret_cast<const float4*>(&h0buf[g * 16 + 4 * q]);
            h0v[2 * q + 0][0] = v.x; h0v[2 * q + 0][1] = v.y;
            h0v[2 * q + 1][0] = v.z; h0v[2 * q + 1][1] = v.w;
        }
        WAVE_SYNC();

        // ---- unpack y0b(t) (bf16 -> f32 pairs)
        v2f yv[8];
        {
            const unsigned uu[8] = { ya.x, ya.y, ya.z, ya.w, yb4.x, yb4.y, yb4.z, yb4.w };
#pragma unroll
            for (int q = 0; q < 8; ++q) yv[q] = bf2_unpack(uu[q]);
        }

        // ---- L1 forward step (input = [h0f(16), y0b(16)], recur h1)
        {
            v2f cr0{}, cr1{}, cz0{}, cz1{}, ci0{}, ci1{}, ch0{}, ch1{};
#pragma unroll
            for (int q = 0; q < 4; ++q) {
                cr0 += w1r[q] * h0v[q];
                cz0 += w1z[q] * h0v[q];
                ci0 += w1n[q] * h0v[q];
            }
#pragma unroll
            for (int q = 4; q < 8; ++q) {
                cr1 += w1r[q] * h0v[q];
                cz1 += w1z[q] * h0v[q];
                ci1 += w1n[q] * h0v[q];
            }
#pragma unroll
            for (int q = 0; q < 4; ++q) {
                cr0 += w1r[8 + q] * yv[q];
                cz0 += w1z[8 + q] * yv[q];
                ci0 += w1n[8 + q] * yv[q];
            }
#pragma unroll
            for (int q = 4; q < 8; ++q) {
                cr1 += w1r[8 + q] * yv[q];
                cz1 += w1z[8 + q] * yv[q];
                ci1 += w1n[8 + q] * yv[q];
            }
#pragma unroll
            for (int q = 0; q < 4; ++q) {
                cr0 += u1r[q] * h1v[q];
                cz0 += u1z[q] * h1v[q];
                ch0 += u1n[q] * h1v[q];
            }
#pragma unroll
            for (int q = 4; q < 8; ++q) {
                cr1 += u1r[q] * h1v[q];
                cz1 += u1z[q] * h1v[q];
                ch1 += u1n[q] * h1v[q];
            }
            float cr  = (cr0[0] + cr0[1]) + (cr1[0] + cr1[1]) + b1r;
            float cz  = (cz0[0] + cz0[1]) + (cz1[0] + cz1[1]) + b1z;
            float ci  = (ci0[0] + ci0[1]) + (ci1[0] + ci1[1]) + b1in;
            float chn = (ch0[0] + ch0[1]) + (ch1[0] + ch1[1]) + b1hn;
            float r = sig_(cr), z = sig_(cz);
            float n = tanh_(fmaf(r, chn, ci));
            h1j = fmaf(z, h1j - n, n);
        }
        h1buf[tid] = h1j;
        WAVE_SYNC();
#pragma unroll
        for (int q = 0; q < 4; ++q) {
            float4 v = *reinterpret_cast<const float4*>(&h1buf[g * 16 + 4 * q]);
            h1v[2 * q + 0][0] = v.x; h1v[2 * q + 0][1] = v.y;
            h1v[2 * q + 1][0] = v.z; h1v[2 * q + 1][1] = v.w;
        }
        WAVE_SYNC();

        ya = na; yb4 = nb4; xv = xn;
    }

    // forward half of the output
    out[(size_t)b * 32 + j] = h1j;

    // ---- L1 backward, single step at t=T-1 from h=0.
    // ya/yb4 still hold y0b[T-1]; h0v holds h0f(T-1).
    float gr = bih1b[j] + bhh1b[j];
    float gz = bih1b[16 + j] + bhh1b[16 + j];
    float gi = bih1b[32 + j];
    const float ghn = bhh1b[32 + j];
    float yv[16];
    {
        const unsigned uu[8] = { ya.x, ya.y, ya.z, ya.w, yb4.x, yb4.y, yb4.z, yb4.w };
#pragma unroll
        for (int q = 0; q < 8; ++q) {
            v2f p = bf2_unpack(uu[q]);
            yv[2 * q] = p[0]; yv[2 * q + 1] = p[1];
        }
    }
    float h0f[16];
#pragma unroll
    for (int q = 0; q < 8; ++q) { h0f[2 * q] = h0v[q][0]; h0f[2 * q + 1] = h0v[q][1]; }
#pragma unroll
    for (int k = 0; k < 16; ++k) {
        gr = fmaf(Wih1b[j * 32 + k],        h0f[k], gr);
        gz = fmaf(Wih1b[(16 + j) * 32 + k], h0f[k], gz);
        gi = fmaf(Wih1b[(32 + j) * 32 + k], h0f[k], gi);
    }
#pragma unroll
    for (int k = 0; k < 16; ++k) {
        gr = fmaf(Wih1b[j * 32 + 16 + k],        yv[k], gr);
        gz = fmaf(Wih1b[(16 + j) * 32 + 16 + k], yv[k], gz);
        gi = fmaf(Wih1b[(32 + j) * 32 + 16 + k], yv[k], gi);
    }
    float rb = sig_(gr), zb = sig_(gz);
    float nb2 = tanh_(fmaf(rb, ghn, gi));
    out[(size_t)b * 32 + 16 + j] = (1.0f - zb) * nb2;
}

extern "C" void kernel_launch(void* const* d_in, const int* in_sizes, int n_in,
                              void* d_out, int out_size, void* d_ws, size_t ws_size,
                              hipStream_t stream) {
    const float* x     = (const float*)d_in[0];
    const float* Wih0f = (const float*)d_in[1];
    const float* Whh0f = (const float*)d_in[2];
    const float* bih0f = (const float*)d_in[3];
    const float* bhh0f = (const float*)d_in[4];
    const float* Wih0b = (const float*)d_in[5];
    const float* Whh0b = (const float*)d_in[6];
    const float* bih0b = (const float*)d_in[7];
    const float* bhh0b = (const float*)d_in[8];
    const float* Wih1f = (const float*)d_in[9];
    const float* Whh1f = (const float*)d_in[10];
    const float* bih1f = (const float*)d_in[11];
    const float* bhh1f = (const float*)d_in[12];
    const float* Wih1b = (const float*)d_in[13];
    const float* Whh1b = (const float*)d_in[14];
    const float* bih1b = (const float*)d_in[15];
    const float* bhh1b = (const float*)d_in[16];
    __hip_bfloat16* y0b = (__hip_bfloat16*)d_ws;   // [T,B,16] bf16 = 64 MiB
    float* out = (float*)d_out;

    // 16 sequences per block (16 groups x 16 lanes) -> B/16 = 256 blocks.
    dim3 grid(B / 16);
    dim3 block(256);
    hipLaunchKernelGGL(k_l0_bwd, grid, block, 0, stream,
                       x, Wih0b, Whh0b, bih0b, bhh0b, y0b);
    hipLaunchKernelGGL(k_fused, grid, block, 0, stream,
                       x, Wih0f, Whh0f, bih0f, bhh0f,
                       Wih1f, Whh1f, bih1f, bhh1f,
                       Wih1b, Whh1b, bih1b, bhh1b,
                       y0b, out);
}